// Round 10
// baseline (5609.301 us; speedup 1.0000x reference)
//
#include <hip/hip_runtime.h>
#include <hip/hip_bf16.h>
#include <stdint.h>

#define BATCH 4
#define SEQ 1024
#define DIMX 1024
#define VOCAB 32000
#define NLAYERS 4
#define NBLK 256

#define W_GARR 4096
#define W_GREL 4608
#define W_LREL 4864
#define W_FLAG 5120

using bf16x8 = __attribute__((ext_vector_type(8))) short;
using f32x4v = __attribute__((ext_vector_type(4))) float;

#define MFMA __builtin_amdgcn_mfma_f32_16x16x32_bf16

__device__ __forceinline__ uint16_t f2b(float f) {
  __hip_bfloat16 h = __float2bfloat16(f);
  return *reinterpret_cast<uint16_t*>(&h);
}
__device__ __forceinline__ float b2f(uint16_t u) {
  __hip_bfloat16 h = *reinterpret_cast<__hip_bfloat16*>(&u);
  return __bfloat162float(h);
}
__device__ __forceinline__ void fsplit(float v, uint16_t& h, uint16_t& l) {
  h = f2b(v);
  l = f2b(v - b2f(h));
}
__device__ __forceinline__ uint32_t get_xcc() {
  uint32_t x;
  asm volatile("s_getreg_b32 %0, hwreg(HW_REG_XCC_ID)" : "=s"(x));
  return x & 7u;
}

// ---------------- embedding gather -> split bf16
__global__ __launch_bounds__(256) void k_embed_split(const int* __restrict__ ids,
                                                     const float* __restrict__ emb,
                                                     uint16_t* __restrict__ Hhi,
                                                     uint16_t* __restrict__ Hlo) {
  int idx = blockIdx.x * 256 + threadIdx.x;
  int d4 = idx & (DIMX / 4 - 1);
  int tb = idx >> 8;
  int t = tb >> 2, b = tb & 3;
  int id = ids[b * SEQ + t];
  float4 v = reinterpret_cast<const float4*>(emb + (size_t)id * DIMX)[d4];
  ushort4 h, l;
  fsplit(v.x, h.x, l.x); fsplit(v.y, h.y, l.y); fsplit(v.z, h.z, l.z); fsplit(v.w, h.w, l.w);
  reinterpret_cast<ushort4*>(Hhi)[idx] = h;
  reinterpret_cast<ushort4*>(Hlo)[idx] = l;
}

// ---------------- split weights: W1 (2048 rows), WS (1024), M1=Wss (1024 -> MP[0])
__global__ __launch_bounds__(256) void k_split_w(const float* __restrict__ W,
                                                 uint16_t* __restrict__ W1h, uint16_t* __restrict__ W1l,
                                                 uint16_t* __restrict__ WSh, uint16_t* __restrict__ WSl,
                                                 uint16_t* __restrict__ M1h, uint16_t* __restrict__ M1l) {
  int idx = blockIdx.x * 256 + threadIdx.x;
  int c4 = idx & 255;
  int row = idx >> 8;
  int l = row >> 12, r = row & 4095;
  const float* Wl = W + (size_t)l * 4 * 1024 * 1024;
  const float* src;
  uint16_t *dh, *dl;
  size_t doff;
  if (r < 2048) { src = Wl + (size_t)r * 2048; dh = W1h; dl = W1l; doff = ((size_t)l * 2048 + r) * 1024; }
  else if (r < 3072) { int rr = r - 2048; src = Wl + (size_t)rr * 2048 + 1024; dh = WSh; dl = WSl; doff = ((size_t)l * 1024 + rr) * 1024; }
  else { int rr = r - 3072; src = Wl + (size_t)(1024 + rr) * 2048 + 1024; dh = M1h; dl = M1l; doff = ((size_t)l * 1024 + rr) * 1024; }
  float4 v = reinterpret_cast<const float4*>(src)[c4];
  ushort4 h, lo4;
  fsplit(v.x, h.x, lo4.x); fsplit(v.y, h.y, lo4.y); fsplit(v.z, h.z, lo4.z); fsplit(v.w, h.w, lo4.w);
  reinterpret_cast<ushort4*>(dh + doff)[c4] = h;
  reinterpret_cast<ushort4*>(dl + doff)[c4] = lo4;
}

// ---------------- T1 = Wss^T per layer
__global__ __launch_bounds__(256) void k_trans_w(const float* __restrict__ W,
                                                 uint16_t* __restrict__ T1h, uint16_t* __restrict__ T1l) {
  __shared__ float t[64][65];
  int l = blockIdx.z;
  const float* Wl = W + (size_t)l * 4 * 1024 * 1024;
  int i0 = blockIdx.y * 64, j0 = blockIdx.x * 64;
  int c4 = (threadIdx.x & 15) * 4, rr = threadIdx.x >> 4;
#pragma unroll
  for (int p = 0; p < 4; ++p) {
    int r = rr + p * 16;
    float4 v = *reinterpret_cast<const float4*>(Wl + (size_t)(1024 + i0 + r) * 2048 + 1024 + j0 + c4);
    t[r][c4] = v.x; t[r][c4 + 1] = v.y; t[r][c4 + 2] = v.z; t[r][c4 + 3] = v.w;
  }
  __syncthreads();
#pragma unroll
  for (int p = 0; p < 4; ++p) {
    int j = rr + p * 16;
    ushort4 h, l4;
    fsplit(t[c4 + 0][j], h.x, l4.x);
    fsplit(t[c4 + 1][j], h.y, l4.y);
    fsplit(t[c4 + 2][j], h.z, l4.z);
    fsplit(t[c4 + 3][j], h.w, l4.w);
    size_t o = (size_t)l * 1024 * 1024 + (size_t)(j0 + j) * 1024 + i0 + c4;
    *reinterpret_cast<ushort4*>(T1h + o) = h;
    *reinterpret_cast<ushort4*>(T1l + o) = l4;
  }
}

// ---------------- split-bf16 MFMA GEMM (NT), 128x128 tile, z-batch
template <int BM, int BN>
__global__ __launch_bounds__(256) void k_mfma(
    int K,
    const uint16_t* __restrict__ Ahi, const uint16_t* __restrict__ Alo, int a_cs, int a_bs, size_t a_z,
    const uint16_t* __restrict__ Bhi, const uint16_t* __restrict__ Blo, int ldb, size_t b_z,
    const float* __restrict__ ADD, int add_cs, int add_bs,
    float* __restrict__ O1f, int o1_cs, int o1_bs,
    uint16_t* __restrict__ O1hi, uint16_t* __restrict__ O1lo, int o1s_cs, int o1s_bs, int split_n0, size_t o1_z,
    uint16_t* __restrict__ O2hi, uint16_t* __restrict__ O2lo, int o2_cs, int o2_bs, size_t o2_z) {
  constexpr int FM = BM / 32;
  constexpr int FN = BN / 32;
  __shared__ uint16_t sAh[BM * 32], sAl[BM * 32], sBh[BN * 32], sBl[BN * 32];
  size_t zb = blockIdx.z;
  Ahi += zb * a_z; Alo += zb * a_z;
  Bhi += zb * b_z; Blo += zb * b_z;
  if (O1hi) { O1hi += zb * o1_z; O1lo += zb * o1_z; }
  if (O2hi) { O2hi += zb * o2_z; O2lo += zb * o2_z; }
  int tid = threadIdx.x;
  int lane = tid & 63;
  int wave = tid >> 6;
  int wm = wave >> 1, wn = wave & 1;
  int m0 = blockIdx.y * BM, n0 = blockIdx.x * BN;
  f32x4v acc[FM][FN] = {};
  for (int kt = 0; kt < K; kt += 32) {
    __syncthreads();
#pragma unroll
    for (int qq = 0; qq < BM / 64; ++qq) {
      int off = qq * 4096 + tid * 16;
      int r = off >> 6;
      int cu = (off & 63) >> 1;
      size_t goff = (size_t)(m0 / 4 + (r >> 2)) * a_cs + (size_t)(r & 3) * a_bs + kt + cu;
      __builtin_amdgcn_global_load_lds(
          (const __attribute__((address_space(1))) uint32_t*)(Ahi + goff),
          (__attribute__((address_space(3))) uint32_t*)((char*)sAh + off), 16, 0, 0);
      __builtin_amdgcn_global_load_lds(
          (const __attribute__((address_space(1))) uint32_t*)(Alo + goff),
          (__attribute__((address_space(3))) uint32_t*)((char*)sAl + off), 16, 0, 0);
    }
#pragma unroll
    for (int qq = 0; qq < BN / 64; ++qq) {
      int off = qq * 4096 + tid * 16;
      int r = off >> 6, cu = (off & 63) >> 1;
      size_t goff = (size_t)(n0 + r) * ldb + kt + cu;
      __builtin_amdgcn_global_load_lds(
          (const __attribute__((address_space(1))) uint32_t*)(Bhi + goff),
          (__attribute__((address_space(3))) uint32_t*)((char*)sBh + off), 16, 0, 0);
      __builtin_amdgcn_global_load_lds(
          (const __attribute__((address_space(1))) uint32_t*)(Blo + goff),
          (__attribute__((address_space(3))) uint32_t*)((char*)sBl + off), 16, 0, 0);
    }
    __syncthreads();
    int rsel = lane & 15, ko = (lane >> 4) * 8;
    bf16x8 ah[FM], al[FM], bh[FN], bl[FN];
#pragma unroll
    for (int mf = 0; mf < FM; ++mf) {
      int row = wm * (FM * 16) + mf * 16 + rsel;
      ah[mf] = *reinterpret_cast<const bf16x8*>(sAh + row * 32 + ko);
      al[mf] = *reinterpret_cast<const bf16x8*>(sAl + row * 32 + ko);
    }
#pragma unroll
    for (int nf = 0; nf < FN; ++nf) {
      int row = wn * (FN * 16) + nf * 16 + rsel;
      bh[nf] = *reinterpret_cast<const bf16x8*>(sBh + row * 32 + ko);
      bl[nf] = *reinterpret_cast<const bf16x8*>(sBl + row * 32 + ko);
    }
#pragma unroll
    for (int mf = 0; mf < FM; ++mf)
#pragma unroll
      for (int nf = 0; nf < FN; ++nf) {
        acc[mf][nf] = MFMA(ah[mf], bh[nf], acc[mf][nf], 0, 0, 0);
        acc[mf][nf] = MFMA(ah[mf], bl[nf], acc[mf][nf], 0, 0, 0);
        acc[mf][nf] = MFMA(al[mf], bh[nf], acc[mf][nf], 0, 0, 0);
      }
  }
  int rowg = (lane >> 4) * 4, colg = lane & 15;
#pragma unroll
  for (int mf = 0; mf < FM; ++mf)
#pragma unroll
    for (int nf = 0; nf < FN; ++nf)
#pragma unroll
      for (int r = 0; r < 4; ++r) {
        int m = m0 + wm * (FM * 16) + mf * 16 + rowg + r;
        int n = n0 + wn * (FN * 16) + nf * 16 + colg;
        size_t ro = (size_t)(m >> 2);
        float dot = acc[mf][nf][r];
        float v = dot;
        if (ADD) v += ADD[ro * add_cs + (size_t)(m & 3) * add_bs + n];
        if (O1f) O1f[ro * o1_cs + (size_t)(m & 3) * o1_bs + n] = v;
        if (O1hi && n >= split_n0) {
          uint16_t h, l;
          fsplit(v, h, l);
          size_t o = ro * o1s_cs + (size_t)(m & 3) * o1s_bs + (n - split_n0);
          O1hi[o] = h; O1lo[o] = l;
        }
        if (O2hi) {
          uint16_t h, l;
          fsplit(dot, h, l);
          size_t o = (o2_bs == 0) ? ((size_t)n * o2_cs + m)
                                  : (ro * o2_cs + (size_t)(m & 3) * o2_bs + n);
          O2hi[o] = h; O2lo[o] = l;
        }
      }
}

// ---------------- grid barrier (round-8 proven: hier 1 wbl2 + 1 inv per XCD; flat fallback)
__device__ __forceinline__ void gbar(uint32_t* S, int flat, uint32_t& gen) {
  gen++;
  __syncthreads();
  int bid = blockIdx.x, tid = threadIdx.x;
  if (flat) {
    if (tid == 0)
      __hip_atomic_store(S + (size_t)bid * 16, gen, __ATOMIC_RELEASE, __HIP_MEMORY_SCOPE_AGENT);
    if (bid == 0) {
      while (__hip_atomic_load(S + (size_t)tid * 16, __ATOMIC_RELAXED, __HIP_MEMORY_SCOPE_AGENT) < gen)
        __builtin_amdgcn_s_sleep(2);
      __syncthreads();
      if (tid == 0) {
        __builtin_amdgcn_fence(__ATOMIC_ACQUIRE, "agent");
        __hip_atomic_store(S + W_GREL, gen, __ATOMIC_RELEASE, __HIP_MEMORY_SCOPE_AGENT);
      }
      __syncthreads();
    } else {
      if (tid == 0) {
        while (__hip_atomic_load(S + W_GREL, __ATOMIC_RELAXED, __HIP_MEMORY_SCOPE_AGENT) < gen)
          __builtin_amdgcn_s_sleep(2);
        __builtin_amdgcn_fence(__ATOMIC_ACQUIRE, "agent");
      }
      __syncthreads();
    }
    return;
  }
  int xcd = bid & 7, q = bid >> 3;
  if (q != 0) {
    if (tid == 0) {
      asm volatile("s_waitcnt vmcnt(0)" ::: "memory");
      __hip_atomic_store(S + (size_t)(xcd * 32 + q) * 16, gen, __ATOMIC_RELAXED, __HIP_MEMORY_SCOPE_AGENT);
      while (__hip_atomic_load(S + W_LREL + xcd * 16, __ATOMIC_RELAXED, __HIP_MEMORY_SCOPE_AGENT) < gen)
        __builtin_amdgcn_s_sleep(1);
      asm volatile("buffer_inv sc0" ::: "memory");
    }
    __builtin_amdgcn_sched_barrier(0);
    __syncthreads();
  } else {
    if (tid < 31) {
      uint32_t* s = S + (size_t)(xcd * 32 + 1 + tid) * 16;
      while (__hip_atomic_load(s, __ATOMIC_RELAXED, __HIP_MEMORY_SCOPE_AGENT) < gen)
        __builtin_amdgcn_s_sleep(1);
    }
    __syncthreads();
    if (tid == 0)
      __hip_atomic_store(S + W_GARR + xcd * 16, gen, __ATOMIC_RELEASE, __HIP_MEMORY_SCOPE_AGENT);
    if (xcd == 0) {
      if (tid < 8) {
        while (__hip_atomic_load(S + W_GARR + tid * 16, __ATOMIC_RELAXED, __HIP_MEMORY_SCOPE_AGENT) < gen)
          __builtin_amdgcn_s_sleep(1);
      }
      __syncthreads();
      if (tid == 0)
        __hip_atomic_store(S + W_GREL, gen, __ATOMIC_RELEASE, __HIP_MEMORY_SCOPE_AGENT);
    }
    if (tid == 0) {
      while (__hip_atomic_load(S + W_GREL, __ATOMIC_RELAXED, __HIP_MEMORY_SCOPE_AGENT) < gen)
        __builtin_amdgcn_s_sleep(1);
      __builtin_amdgcn_fence(__ATOMIC_ACQUIRE, "agent");
      __hip_atomic_store(S + W_LREL + xcd * 16, gen, __ATOMIC_RELEASE, __HIP_MEMORY_SCOPE_AGENT);
    }
    __builtin_amdgcn_sched_barrier(0);
    __syncthreads();
  }
}

// ---------------- dual-n 16x16xK tile: per-lane A pointers; B from LDS (2 tiles share A)
__device__ __forceinline__ void wtile_dual(
    const uint16_t* __restrict__ pah, const uint16_t* __restrict__ pal,
    const uint16_t* sB0, const uint16_t* sB1,
    int rsel, int ko, f32x4v& out0, f32x4v& out1) {
  int s7 = rsel & 7;
  int rb0 = rsel * 1024, rb1 = rb0 + 16 * 1024;
  f32x4v a0 = {0.f, 0.f, 0.f, 0.f}, a1 = {0.f, 0.f, 0.f, 0.f};
#pragma unroll 4
  for (int kt = 0; kt < 1024; kt += 32) {
    int sw = ((((kt + ko) >> 3) ^ s7) << 3);
    bf16x8 ah = *reinterpret_cast<const bf16x8*>(pah + kt);
    bf16x8 al = *reinterpret_cast<const bf16x8*>(pal + kt);
    bf16x8 b0h = *reinterpret_cast<const bf16x8*>(sB0 + rb0 + sw);
    bf16x8 b0l = *reinterpret_cast<const bf16x8*>(sB1 + rb0 + sw);
    bf16x8 b1h = *reinterpret_cast<const bf16x8*>(sB0 + rb1 + sw);
    bf16x8 b1l = *reinterpret_cast<const bf16x8*>(sB1 + rb1 + sw);
    a0 = MFMA(ah, b0h, a0, 0, 0, 0); a1 = MFMA(ah, b1h, a1, 0, 0, 0);
    a0 = MFMA(ah, b0l, a0, 0, 0, 0); a1 = MFMA(ah, b1l, a1, 0, 0, 0);
    a0 = MFMA(al, b0h, a0, 0, 0, 0); a1 = MFMA(al, b1h, a1, 0, 0, 0);
  }
  out0 = a0; out1 = a1;
}

// ---------------- persistent per-layer kernel: LOG-DEPTH scan (16 barrier-steps).
// Phase A: chunk-sum tree (4 steps, A^1..A^8). Phase B: boundary Hillis-Steele over 64
// chunks (pre + 6 steps, A16^(2^s)). Phase C: seeded in-chunk H-S producing S directly
// (init + 4 steps, A^1..A^8). XCD x owns chunks [8x,8x+8) for A/C locality.
__global__ __launch_bounds__(256) void k_layer(
    uint32_t* S,
    const float* __restrict__ P,
    const uint16_t* __restrict__ PUh, const uint16_t* __restrict__ PUl,
    uint16_t* __restrict__ Sh, uint16_t* __restrict__ Sl,
    const uint16_t* __restrict__ MPh, const uint16_t* __restrict__ MPl, size_t mpk,
    uint16_t* RAh, uint16_t* RAl, uint16_t* RBh, uint16_t* RBl,
    uint16_t* Eah, uint16_t* Eal, uint16_t* Ebh, uint16_t* Ebl,
    uint16_t* SIG0h, uint16_t* SIG0l,
    uint16_t* Xbh, uint16_t* Xbl,
    const float* __restrict__ starterL) {
  __shared__ uint16_t sB[2][32 * 1024];   // 128 KB B-slice (32 rows, swizzled)
  int tid = threadIdx.x, bid = blockIdx.x;
  int lane = tid & 63, wv = tid >> 6;
  int xcd = bid & 7, q = bid >> 3;
  int rsel = lane & 15, ko = (lane >> 4) * 8;
  int rowg = (lane >> 4) * 4, colg = lane & 15;
  int c0 = xcd * 8;
  int nA = q * 32 + colg, nB = nA + 16;      // A/C phase n columns (block slice q*32)
  uint32_t gen = 0;

  // SIG0 = starter broadcast into 16 rows (split)
  {
    int idx = bid * 256 + tid;
    if (idx < 16 * 1024) {
      int d = idx & 1023;
      uint16_t h, l;
      fsplit(starterL[d], h, l);
      SIG0h[idx] = h; SIG0l[idx] = l;
    }
  }

  if (tid == 0 && get_xcc() != (uint32_t)xcd)
    __hip_atomic_store(S + W_FLAG, 1u, __ATOMIC_RELAXED, __HIP_MEMORY_SCOPE_AGENT);
  gbar(S, 1, gen);
  int flat = (int)__hip_atomic_load(S + W_FLAG, __ATOMIC_RELAXED, __HIP_MEMORY_SCOPE_AGENT);

  auto stage = [&](int k, int row0) {
    const uint16_t* Bh = MPh + (size_t)k * mpk;
    const uint16_t* Bl = MPl + (size_t)k * mpk;
    for (int i = tid; i < 32 * 128; i += 256) {
      int r = i >> 7, c8 = i & 127;
      int dst = r * 1024 + ((c8 ^ (r & 7)) << 3);
      *reinterpret_cast<bf16x8*>(&sB[0][dst]) = *reinterpret_cast<const bf16x8*>(Bh + (size_t)(row0 + r) * 1024 + c8 * 8);
      *reinterpret_cast<bf16x8*>(&sB[1][dst]) = *reinterpret_cast<const bf16x8*>(Bl + (size_t)(row0 + r) * 1024 + c8 * 8);
    }
  };

  // ===== PHASE A level 1: RA[c][k] = A*u_{2k} + u_{2k+1}  (nL=8, 16 m-tiles)
  stage(0, q * 32);
  __syncthreads();
  for (int mt = wv; mt < 16; mt += 4) {
    int r = mt * 16 + rsel, b = r & 3, v = r >> 2;
    int kk = v & 7, cl = v >> 3;
    size_t ao = ((size_t)((c0 + cl) * 16 + 2 * kk) * 4 + b) * 1024 + ko;
    f32x4v o0, o1;
    wtile_dual(PUh + ao, PUl + ao, sB[0], sB[1], rsel, ko, o0, o1);
#pragma unroll
    for (int rr = 0; rr < 4; ++rr) {
      int m = mt * 16 + rowg + rr, b2 = m & 3, v2 = m >> 2;
      int k2 = v2 & 7, c2 = c0 + (v2 >> 3);
      size_t po = ((size_t)(c2 * 16 + 2 * k2 + 1) * 4 + b2) * 2048 + 1024;
      size_t oo = ((size_t)(c2 * 8 + k2) * 4 + b2) * 1024;
      float v0 = o0[rr] + P[po + nA];
      float v1 = o1[rr] + P[po + nB];
      uint16_t h, l;
      fsplit(v0, h, l); RAh[oo + nA] = h; RAl[oo + nA] = l;
      fsplit(v1, h, l); RAh[oo + nB] = h; RAl[oo + nB] = l;
    }
  }
  gbar(S, flat, gen);

  // ===== PHASE A levels 2,3 (generic tree level)
  auto treeLevel = [&](int Bk, int nLlog, int mtN,
                       const uint16_t* inH, const uint16_t* inL,
                       uint16_t* outH, uint16_t* outL) {
    stage(Bk, q * 32);
    __syncthreads();
    int nL = 1 << nLlog;
    for (int mt = wv; mt < mtN; mt += 4) {
      int r = mt * 16 + rsel, b = r & 3, v = r >> 2;
      int kk = v & (nL - 1), cl = v >> nLlog;
      size_t ao = ((size_t)((c0 + cl) * 8 + 2 * kk) * 4 + b) * 1024 + ko;
      f32x4v o0, o1;
      wtile_dual(inH + ao, inL + ao, sB[0], sB[1], rsel, ko, o0, o1);
#pragma unroll
      for (int rr = 0; rr < 4; ++rr) {
        int m = mt * 16 + rowg + rr, b2 = m & 3, v2 = m >> 2;
        int k2 = v2 & (nL - 1), c2 = c0 + (v2 >> nLlog);
        size_t po = ((size_t)(c2 * 8 + 2 * k2 + 1) * 4 + b2) * 1024;
        size_t oo = ((size_t)(c2 * 8 + k2) * 4 + b2) * 1024;
        float r0 = b2f(inH[po + nA]) + b2f(inL[po + nA]) + o0[rr];
        float r1 = b2f(inH[po + nB]) + b2f(inL[po + nB]) + o1[rr];
        uint16_t h, l;
        fsplit(r0, h, l); outH[oo + nA] = h; outL[oo + nA] = l;
        fsplit(r1, h, l); outH[oo + nB] = h; outL[oo + nB] = l;
      }
    }
    gbar(S, flat, gen);
  };
  treeLevel(1, 2, 8, RAh, RAl, RBh, RBl);   // level 2 (nL=4)
  treeLevel(2, 1, 4, RBh, RBl, RAh, RAl);   // level 3 (nL=2)

  // ===== PHASE A level 4: E[c] = A^8 * r[c][0] + r[c][1]  (2 m-tiles)
  stage(3, q * 32);
  __syncthreads();
  for (int mt = wv; mt < 2; mt += 4) {
    int r = mt * 16 + rsel, b = r & 3, v = r >> 2;   // v 0..7 = cl
    size_t ao = ((size_t)((c0 + v) * 8) * 4 + b) * 1024 + ko;
    f32x4v o0, o1;
    wtile_dual(RAh + ao, RAl + ao, sB[0], sB[1], rsel, ko, o0, o1);
#pragma unroll
    for (int rr = 0; rr < 4; ++rr) {
      int m = mt * 16 + rowg + rr, b2 = m & 3, v2 = m >> 2;
      int c2 = c0 + v2;
      size_t po = ((size_t)(c2 * 8 + 1) * 4 + b2) * 1024;
      size_t eo = ((size_t)(c2 * 4 + b2)) * 1024;
      float r0 = b2f(RAh[po + nA]) + b2f(RAl[po + nA]) + o0[rr];
      float r1 = b2f(RAh[po + nB]) + b2f(RAl[po + nB]) + o1[rr];
      uint16_t h, l;
      fsplit(r0, h, l); Eah[eo + nA] = h; Eal[eo + nA] = l;
      fsplit(r1, h, l); Eah[eo + nB] = h; Eal[eo + nB] = l;
    }
  }
  gbar(S, flat, gen);

  // ===== PHASE B: active blocks q<4, n-slice (xcd*4+q)*32
  int nbase = (xcd * 4 + q) * 32;
  int nAB = nbase + colg, nBB = nAB + 16;

  // pre: E[0] += A16 * sigma0
  if (q < 4) stage(4, nbase);
  __syncthreads();
  if (q < 4 && wv == 0) {
    size_t ao = (size_t)rsel * 1024 + ko;
    f32x4v o0, o1;
    wtile_dual(SIG0h + ao, SIG0l + ao, sB[0], sB[1], rsel, ko, o0, o1);
#pragma unroll
    for (int rr = 0; rr < 4; ++rr) {
      int m = rowg + rr, b2 = m & 3, cp = m >> 2;
      if (cp == 0) {
        size_t eo = (size_t)b2 * 1024;
        float r0 = b2f(Eah[eo + nAB]) + b2f(Eal[eo + nAB]) + o0[rr];
        float r1 = b2f(Eah[eo + nBB]) + b2f(Eal[eo + nBB]) + o1[rr];
        uint16_t h, l;
        fsplit(r0, h, l); Eah[eo + nAB] = h; Eal[eo + nAB] = l;
        fsplit(r1, h, l); Eah[eo + nBB] = h; Eal[eo + nBB] = l;
      }
    }
  }
  gbar(S, flat, gen);

  // HS steps s=0..5 with powers A16^(2^s) = MP[4+s]
  for (int s = 0; s < 6; ++s) {
    int p = 1 << s;
    const uint16_t* Eoh = (s & 1) ? Ebh : Eah;
    const uint16_t* Eol = (s & 1) ? Ebl : Eal;
    uint16_t* Enh = (s & 1) ? Eah : Ebh;
    uint16_t* Enl = (s & 1) ? Eal : Ebl;
    if (q < 4) stage(4 + s, nbase);
    __syncthreads();
    if (q < 4) {
      for (int mt = wv; mt < 16; mt += 4) {
        int r = mt * 16 + rsel, b = r & 3, c = r >> 2;
        int cin = (c >= p) ? (c - p) : c;
        size_t ao = ((size_t)(cin * 4 + b)) * 1024 + ko;
        f32x4v o0, o1;
        wtile_dual(Eoh + ao, Eol + ao, sB[0], sB[1], rsel, ko, o0, o1);
#pragma unroll
        for (int rr = 0; rr < 4; ++rr) {
          int m = mt * 16 + rowg + rr, b2 = m & 3, c2 = m >> 2;
          size_t eo = ((size_t)(c2 * 4 + b2)) * 1024;
          if (c2 >= p) {
            float r0 = b2f(Eoh[eo + nAB]) + b2f(Eol[eo + nAB]) + o0[rr];
            float r1 = b2f(Eoh[eo + nBB]) + b2f(Eol[eo + nBB]) + o1[rr];
            uint16_t h, l;
            fsplit(r0, h, l); Enh[eo + nAB] = h; Enl[eo + nAB] = l;
            fsplit(r1, h, l); Enh[eo + nBB] = h; Enl[eo + nBB] = l;
          } else {
            Enh[eo + nAB] = Eoh[eo + nAB]; Enl[eo + nAB] = Eol[eo + nAB];
            Enh[eo + nBB] = Eoh[eo + nBB]; Enl[eo + nBB] = Eol[eo + nBB];
          }
        }
      }
    }
    gbar(S, flat, gen);
  }
  // final boundary values in Ea: Ea[c] = sigma_{c+1}

  // ===== PHASE C init: X[c*16] = sigma_c ; X[c*16+j] = u[c*16+j-1]  (into Sh/Sl = Xa)
  {
    int xt = q * 256 + tid;   // XCD-thread id 0..8191
    for (int u = xt; u < 128 * 1024; u += 8192) {  // float4 units: 128 t x 4 b x 256
      int tl = u >> 10, b = (u >> 8) & 3, d4 = u & 255;
      int t = c0 * 16 + tl;
      int j = tl & 15;
      int c = c0 + (tl >> 4);
      float4 val;
      if (j == 0) {
        if (c == 0) {
          val = reinterpret_cast<const float4*>(starterL)[d4];
        } else {
          size_t eo = ((size_t)((c - 1) * 4 + b)) * 1024 + d4 * 4;
          ushort4 hh = *reinterpret_cast<const ushort4*>(Eah + eo);
          ushort4 ll = *reinterpret_cast<const ushort4*>(Eal + eo);
          val.x = b2f(hh.x) + b2f(ll.x);
          val.y = b2f(hh.y) + b2f(ll.y);
          val.z = b2f(hh.z) + b2f(ll.z);
          val.w = b2f(hh.w) + b2f(ll.w);
        }
      } else {
        val = *reinterpret_cast<const float4*>(P + ((size_t)(t - 1) * 4 + b) * 2048 + 1024 + d4 * 4);
      }
      size_t xo = ((size_t)t * 4 + b) * 1024 + d4 * 4;
      ushort4 h4, l4;
      fsplit(val.x, h4.x, l4.x); fsplit(val.y, h4.y, l4.y);
      fsplit(val.z, h4.z, l4.z); fsplit(val.w, h4.w, l4.w);
      *reinterpret_cast<ushort4*>(Sh + xo) = h4;
      *reinterpret_cast<ushort4*>(Sl + xo) = l4;
    }
  }
  gbar(S, flat, gen);

  // ===== PHASE C HS steps s=0..3 with powers A^(2^s) = MP[s]
  for (int s = 0; s < 4; ++s) {
    int p = 1 << s;
    const uint16_t* Xoh = (s & 1) ? Xbh : Sh;
    const uint16_t* Xol = (s & 1) ? Xbl : Sl;
    uint16_t* Xnh = (s & 1) ? Sh : Xbh;
    uint16_t* Xnl = (s & 1) ? Sl : Xbl;
    stage(s, q * 32);
    __syncthreads();
    for (int mt = wv; mt < 32; mt += 4) {
      int r = mt * 16 + rsel, b = r & 3, v = r >> 2;
      int j = v & 15, cl = v >> 4;
      int jin = (j >= p) ? (j - p) : j;
      size_t ao = ((size_t)((c0 + cl) * 16 + jin) * 4 + b) * 1024 + ko;
      f32x4v o0, o1;
      wtile_dual(Xoh + ao, Xol + ao, sB[0], sB[1], rsel, ko, o0, o1);
#pragma unroll
      for (int rr = 0; rr < 4; ++rr) {
        int m = mt * 16 + rowg + rr, b2 = m & 3, v2 = m >> 2;
        int j2 = v2 & 15, cl2 = v2 >> 4;
        size_t xo = ((size_t)((c0 + cl2) * 16 + j2) * 4 + b2) * 1024;
        if (j2 >= p) {
          float r0 = b2f(Xoh[xo + nA]) + b2f(Xol[xo + nA]) + o0[rr];
          float r1 = b2f(Xoh[xo + nB]) + b2f(Xol[xo + nB]) + o1[rr];
          uint16_t h, l;
          fsplit(r0, h, l); Xnh[xo + nA] = h; Xnl[xo + nA] = l;
          fsplit(r1, h, l); Xnh[xo + nB] = h; Xnl[xo + nB] = l;
        } else {
          Xnh[xo + nA] = Xoh[xo + nA]; Xnl[xo + nA] = Xol[xo + nA];
          Xnh[xo + nB] = Xoh[xo + nB]; Xnl[xo + nB] = Xol[xo + nB];
        }
      }
    }
    if (s < 3) gbar(S, flat, gen);
  }
  // final S (split) in Sh/Sl (s=3 writes Sh/Sl)
}

// ---------------- reorder H_hi [t][b][d] -> Y [b][t][d]
__global__ __launch_bounds__(256) void k_reorder_hi(const uint16_t* __restrict__ Hhi, uint16_t* __restrict__ Y) {
  int idx = blockIdx.x * 256 + threadIdx.x;
  int d4 = idx & (DIMX / 4 - 1);
  int tb = idx >> 8;
  int t = tb >> 2, b = tb & 3;
  ushort4 v = reinterpret_cast<const ushort4*>(Hhi)[idx];
  reinterpret_cast<ushort4*>(Y + (size_t)(b * SEQ + t) * DIMX)[d4] = v;
}

__global__ __launch_bounds__(256) void k_cast_w(const float* __restrict__ src, uint16_t* __restrict__ dst, int n4) {
  int idx = blockIdx.x * 256 + threadIdx.x;
  if (idx >= n4) return;
  float4 v = reinterpret_cast<const float4*>(src)[idx];
  ushort4 o;
  o.x = f2b(v.x); o.y = f2b(v.y); o.z = f2b(v.z); o.w = f2b(v.w);
  reinterpret_cast<ushort4*>(dst)[idx] = o;
}

// ---------------- logits GEMM: bf16 MFMA 128x128
__global__ __launch_bounds__(256) void k_logits(const uint16_t* __restrict__ A,
                                                const uint16_t* __restrict__ Bt,
                                                float* __restrict__ C) {
  __shared__ uint16_t As[128 * 32];
  __shared__ uint16_t Bs[128 * 32];
  int tid = threadIdx.x;
  int bx = blockIdx.x, by = blockIdx.y;
  int lane = tid & 63, wave = tid >> 6;
  int wm = wave >> 1, wn = wave & 1;
  f32x4v acc[4][4] = {};
  const uint16_t* Ag = A + (size_t)by * 128 * 1024;
  const uint16_t* Bg = Bt + (size_t)bx * 128 * 1024;
  for (int kt = 0; kt < 1024; kt += 32) {
    __syncthreads();
#pragma unroll
    for (int qq = 0; qq < 2; ++qq) {
      int off = qq * 4096 + tid * 16;
      int r = off >> 6, cu = (off & 63) >> 1;
      __builtin_amdgcn_global_load_lds(
          (const __attribute__((address_space(1))) uint32_t*)(Ag + (size_t)r * 1024 + kt + cu),
          (__attribute__((address_space(3))) uint32_t*)((char*)As + off), 16, 0, 0);
      __builtin_amdgcn_global_load_lds(
          (const __attribute__((address_space(1))) uint32_t*)(Bg + (size_t)r * 1024 + kt + cu),
          (__attribute__((address_space(3))) uint32_t*)((char*)Bs + off), 16, 0, 0);
    }
    __syncthreads();
    int rsel = lane & 15, ko = (lane >> 4) * 8;
    bf16x8 af[4], bfr[4];
#pragma unroll
    for (int mf = 0; mf < 4; ++mf)
      af[mf] = *reinterpret_cast<const bf16x8*>(As + (wm * 64 + mf * 16 + rsel) * 32 + ko);
#pragma unroll
    for (int nf = 0; nf < 4; ++nf)
      bfr[nf] = *reinterpret_cast<const bf16x8*>(Bs + (wn * 64 + nf * 16 + rsel) * 32 + ko);
#pragma unroll
    for (int mf = 0; mf < 4; ++mf)
#pragma unroll
      for (int nf = 0; nf < 4; ++nf)
        acc[mf][nf] = MFMA(af[mf], bfr[nf], acc[mf][nf], 0, 0, 0);
  }
  int rowg = (lane >> 4) * 4;
  int colg = lane & 15;
#pragma unroll
  for (int mf = 0; mf < 4; ++mf)
#pragma unroll
    for (int nf = 0; nf < 4; ++nf)
#pragma unroll
      for (int r = 0; r < 4; ++r) {
        int m = by * 128 + wm * 64 + mf * 16 + rowg + r;
        int n = bx * 128 + wn * 64 + nf * 16 + colg;
        C[(size_t)m * VOCAB + n] = acc[mf][nf][r];
      }
}

// =========================================================================
extern "C" void kernel_launch(void* const* d_in, const int* in_sizes, int n_in,
                              void* d_out, int out_size, void* d_ws, size_t ws_size,
                              hipStream_t stream) {
  const int* ids = (const int*)d_in[0];
  const float* emb = (const float*)d_in[1];
  const float* W = (const float*)d_in[2];
  const float* outw = (const float*)d_in[3];
  const float* starter = (const float*)d_in[4];
  float* out = (float*)d_out;

  char* wsb = (char*)d_ws;
  size_t off = 0;
  auto alloc = [&](size_t bytes) {
    void* p = wsb + off;
    off = (off + bytes + 255) & ~(size_t)255;
    return p;
  };
  const size_t TB = SEQ * BATCH;
  const size_t MB1 = (size_t)1024 * 1024;

  uint32_t* SYNC = (uint32_t*)alloc((size_t)NLAYERS * 8192 * 4);
  uint16_t* Hh[2] = {(uint16_t*)alloc(TB * DIMX * 2), (uint16_t*)alloc(TB * DIMX * 2)};
  uint16_t* Hl[2] = {(uint16_t*)alloc(TB * DIMX * 2), (uint16_t*)alloc(TB * DIMX * 2)};
  float* P = (float*)alloc(TB * 2 * DIMX * 4);
  uint16_t* PUh = (uint16_t*)alloc(TB * DIMX * 2);
  uint16_t* PUl = (uint16_t*)alloc(TB * DIMX * 2);
  uint16_t* Sh = (uint16_t*)alloc(TB * DIMX * 2);
  uint16_t* Sl = (uint16_t*)alloc(TB * DIMX * 2);
  uint16_t* W1h = (uint16_t*)alloc((size_t)NLAYERS * 2048 * 1024 * 2);
  uint16_t* W1l = (uint16_t*)alloc((size_t)NLAYERS * 2048 * 1024 * 2);
  uint16_t* WSh = (uint16_t*)alloc((size_t)NLAYERS * MB1 * 2);
  uint16_t* WSl = (uint16_t*)alloc((size_t)NLAYERS * MB1 * 2);
  uint16_t* T1h = (uint16_t*)alloc((size_t)NLAYERS * MB1 * 2);
  uint16_t* T1l = (uint16_t*)alloc((size_t)NLAYERS * MB1 * 2);
  uint16_t* TPh[2] = {(uint16_t*)alloc((size_t)NLAYERS * MB1 * 2), (uint16_t*)alloc((size_t)NLAYERS * MB1 * 2)};
  uint16_t* TPl[2] = {(uint16_t*)alloc((size_t)NLAYERS * MB1 * 2), (uint16_t*)alloc((size_t)NLAYERS * MB1 * 2)};
  // MP[k][layer]: k=0..9 -> A^(2^k)
  uint16_t* MPh = (uint16_t*)alloc((size_t)10 * NLAYERS * MB1 * 2);
  uint16_t* MPl = (uint16_t*)alloc((size_t)10 * NLAYERS * MB1 * 2);
  uint16_t* RAh = (uint16_t*)alloc((size_t)64 * 8 * 4 * 1024 * 2);
  uint16_t* RAl = (uint16_t*)alloc((size_t)64 * 8 * 4 * 1024 * 2);
  uint16_t* RBh = (uint16_t*)alloc((size_t)64 * 8 * 4 * 1024 * 2);
  uint16_t* RBl = (uint16_t*)alloc((size_t)64 * 8 * 4 * 1024 * 2);
  uint16_t* Eah = (uint16_t*)alloc((size_t)64 * 4 * 1024 * 2);
  uint16_t* Eal = (uint16_t*)alloc((size_t)64 * 4 * 1024 * 2);
  uint16_t* Ebh = (uint16_t*)alloc((size_t)64 * 4 * 1024 * 2);
  uint16_t* Ebl = (uint16_t*)alloc((size_t)64 * 4 * 1024 * 2);
  uint16_t* SIG0h = (uint16_t*)alloc((size_t)16 * 1024 * 2);
  uint16_t* SIG0l = (uint16_t*)alloc((size_t)16 * 1024 * 2);
  uint16_t* Xbh = (uint16_t*)alloc(TB * DIMX * 2);
  uint16_t* Xbl = (uint16_t*)alloc(TB * DIMX * 2);
  uint16_t* YSB = (uint16_t*)alloc(TB * DIMX * 2);
  uint16_t* OWB = (uint16_t*)alloc((size_t)VOCAB * DIMX * 2);

  hipMemsetAsync(SYNC, 0, (size_t)NLAYERS * 8192 * 4, stream);
  // M1 -> MP[0]
  k_split_w<<<NLAYERS * 4096, 256, 0, stream>>>(W, W1h, W1l, WSh, WSl, MPh, MPl);
  k_trans_w<<<dim3(16, 16, NLAYERS), 256, 0, stream>>>(W, T1h, T1l);
  k_cast_w<<<(int)((size_t)VOCAB * DIMX / 4 / 256), 256, 0, stream>>>(outw, OWB, VOCAB * DIMX / 4);
  k_embed_split<<<(int)(TB * DIMX / 4 / 256), 256, 0, stream>>>(ids, emb, Hh[0], Hl[0]);

  // power chain k=1..9: MP[k] = MP[k-1]^2 ; T ping-pong (T output through k=8)
  {
    const size_t kstr = (size_t)NLAYERS * MB1;
    for (int k = 1; k <= 9; ++k) {
      const uint16_t* inMh = MPh + (size_t)(k - 1) * kstr;
      const uint16_t* inMl = MPl + (size_t)(k - 1) * kstr;
      const uint16_t* inTh = (k == 1) ? T1h : TPh[(k - 1) & 1];
      const uint16_t* inTl = (k == 1) ? T1l : TPl[(k - 1) & 1];
      uint16_t* oMh = MPh + (size_t)k * kstr;
      uint16_t* oMl = MPl + (size_t)k * kstr;
      uint16_t* oTh = (k <= 8) ? TPh[k & 1] : nullptr;
      uint16_t* oTl = (k <= 8) ? TPl[k & 1] : nullptr;
      k_mfma<128, 128><<<dim3(8, 8, NLAYERS), 256, 0, stream>>>(
          1024,
          inMh, inMl, 4096, 1024, MB1,
          inTh, inTl, 1024, MB1,
          nullptr, 0, 0,
          nullptr, 0, 0,
          oMh, oMl, 4096, 1024, 0, MB1,
          oTh, oTl, 1024, 0, MB1);
    }
  }

  int cur = 0;
  for (int l = 0; l < NLAYERS; ++l) {
    // [a|u] = H @ W[:,0:1024]^T ; f32 -> P, split(u) -> PU
    k_mfma<128, 128><<<dim3(16, 32, 1), 256, 0, stream>>>(
        1024,
        Hh[cur], Hl[cur], 4096, 1024, 0,
        W1h + (size_t)l * 2048 * 1024, W1l + (size_t)l * 2048 * 1024, 1024, 0,
        nullptr, 0, 0,
        P, 8192, 2048,
        PUh, PUl, 4096, 1024, 1024, 0,
        nullptr, nullptr, 0, 1, 0);

    // persistent log-depth scan
    k_layer<<<NBLK, 256, 0, stream>>>(
        SYNC + (size_t)l * 8192,
        P, PUh, PUl, Sh, Sl,
        MPh + (size_t)l * MB1, MPl + (size_t)l * MB1, (size_t)NLAYERS * MB1,
        RAh, RAl, RBh, RBl,
        Eah, Eal, Ebh, Ebl,
        SIG0h, SIG0l,
        Xbh, Xbl,
        starter + (size_t)l * DIMX);

    // H_next = a + S @ W_hs^T (split out)
    k_mfma<128, 128><<<dim3(8, 32, 1), 256, 0, stream>>>(
        1024,
        Sh, Sl, 4096, 1024, 0,
        WSh + (size_t)l * MB1, WSl + (size_t)l * MB1, 1024, 0,
        P, 8192, 2048,
        nullptr, 0, 0,
        Hh[cur ^ 1], Hl[cur ^ 1], 4096, 1024, 0, 0,
        nullptr, nullptr, 0, 1, 0);
    cur ^= 1;
  }

  k_reorder_hi<<<(int)(TB * DIMX / 4 / 256), 256, 0, stream>>>(Hh[cur], YSB);
  k_logits<<<dim3(VOCAB / 128, TB / 128), 256, 0, stream>>>(YSB, OWB, out);
}

// Round 11
// 5540.276 us; speedup vs baseline: 1.0125x; 1.0125x over previous
//
#include <hip/hip_runtime.h>
#include <hip/hip_bf16.h>
#include <stdint.h>

#define BATCH 4
#define SEQ 1024
#define DIMX 1024
#define VOCAB 32000
#define NLAYERS 4

using bf16x8 = __attribute__((ext_vector_type(8))) short;
using f32x4v = __attribute__((ext_vector_type(4))) float;

#define MFMA __builtin_amdgcn_mfma_f32_16x16x32_bf16

__device__ __forceinline__ uint16_t f2b(float f) {
  __hip_bfloat16 h = __float2bfloat16(f);
  return *reinterpret_cast<uint16_t*>(&h);
}
__device__ __forceinline__ float b2f(uint16_t u) {
  __hip_bfloat16 h = *reinterpret_cast<__hip_bfloat16*>(&u);
  return __bfloat162float(h);
}
__device__ __forceinline__ void fsplit(float v, uint16_t& h, uint16_t& l) {
  h = f2b(v);
  l = f2b(v - b2f(h));
}

// ---------------- embedding gather -> split bf16
__global__ __launch_bounds__(256) void k_embed_split(const int* __restrict__ ids,
                                                     const float* __restrict__ emb,
                                                     uint16_t* __restrict__ Hhi,
                                                     uint16_t* __restrict__ Hlo) {
  int idx = blockIdx.x * 256 + threadIdx.x;
  int d4 = idx & (DIMX / 4 - 1);
  int tb = idx >> 8;
  int t = tb >> 2, b = tb & 3;
  int id = ids[b * SEQ + t];
  float4 v = reinterpret_cast<const float4*>(emb + (size_t)id * DIMX)[d4];
  ushort4 h, l;
  fsplit(v.x, h.x, l.x); fsplit(v.y, h.y, l.y); fsplit(v.z, h.z, l.z); fsplit(v.w, h.w, l.w);
  reinterpret_cast<ushort4*>(Hhi)[idx] = h;
  reinterpret_cast<ushort4*>(Hlo)[idx] = l;
}

// ---------------- split weights: W1 (2048 rows), WS (1024), M1=Wss (1024 -> MP[0])
__global__ __launch_bounds__(256) void k_split_w(const float* __restrict__ W,
                                                 uint16_t* __restrict__ W1h, uint16_t* __restrict__ W1l,
                                                 uint16_t* __restrict__ WSh, uint16_t* __restrict__ WSl,
                                                 uint16_t* __restrict__ M1h, uint16_t* __restrict__ M1l) {
  int idx = blockIdx.x * 256 + threadIdx.x;
  int c4 = idx & 255;
  int row = idx >> 8;
  int l = row >> 12, r = row & 4095;
  const float* Wl = W + (size_t)l * 4 * 1024 * 1024;
  const float* src;
  uint16_t *dh, *dl;
  size_t doff;
  if (r < 2048) { src = Wl + (size_t)r * 2048; dh = W1h; dl = W1l; doff = ((size_t)l * 2048 + r) * 1024; }
  else if (r < 3072) { int rr = r - 2048; src = Wl + (size_t)rr * 2048 + 1024; dh = WSh; dl = WSl; doff = ((size_t)l * 1024 + rr) * 1024; }
  else { int rr = r - 3072; src = Wl + (size_t)(1024 + rr) * 2048 + 1024; dh = M1h; dl = M1l; doff = ((size_t)l * 1024 + rr) * 1024; }
  float4 v = reinterpret_cast<const float4*>(src)[c4];
  ushort4 h, lo4;
  fsplit(v.x, h.x, lo4.x); fsplit(v.y, h.y, lo4.y); fsplit(v.z, h.z, lo4.z); fsplit(v.w, h.w, lo4.w);
  reinterpret_cast<ushort4*>(dh + doff)[c4] = h;
  reinterpret_cast<ushort4*>(dl + doff)[c4] = lo4;
}

// ---------------- T1 = Wss^T per layer
__global__ __launch_bounds__(256) void k_trans_w(const float* __restrict__ W,
                                                 uint16_t* __restrict__ T1h, uint16_t* __restrict__ T1l) {
  __shared__ float t[64][65];
  int l = blockIdx.z;
  const float* Wl = W + (size_t)l * 4 * 1024 * 1024;
  int i0 = blockIdx.y * 64, j0 = blockIdx.x * 64;
  int c4 = (threadIdx.x & 15) * 4, rr = threadIdx.x >> 4;
#pragma unroll
  for (int p = 0; p < 4; ++p) {
    int r = rr + p * 16;
    float4 v = *reinterpret_cast<const float4*>(Wl + (size_t)(1024 + i0 + r) * 2048 + 1024 + j0 + c4);
    t[r][c4] = v.x; t[r][c4 + 1] = v.y; t[r][c4 + 2] = v.z; t[r][c4 + 3] = v.w;
  }
  __syncthreads();
#pragma unroll
  for (int p = 0; p < 4; ++p) {
    int j = rr + p * 16;
    ushort4 h, l4;
    fsplit(t[c4 + 0][j], h.x, l4.x);
    fsplit(t[c4 + 1][j], h.y, l4.y);
    fsplit(t[c4 + 2][j], h.z, l4.z);
    fsplit(t[c4 + 3][j], h.w, l4.w);
    size_t o = (size_t)l * 1024 * 1024 + (size_t)(j0 + j) * 1024 + i0 + c4;
    *reinterpret_cast<ushort4*>(T1h + o) = h;
    *reinterpret_cast<ushort4*>(T1l + o) = l4;
  }
}

// ---------------- split-bf16 MFMA GEMM (NT), 128x128 tile, z-batch, masked-scan support.
// out[m][n] = dot(m,n) + add(m,n); if mask_lim && ((m>>2)&mask_and) < mask_lim: out = add
// add from ADDf (f32) or ADDsh/ADDsl (split bf16). A rows: (m>>2)*a_cs + (m&3)*a_bs.
template <int BM, int BN>
__global__ __launch_bounds__(256) void k_mfma(
    int K,
    const uint16_t* __restrict__ Ahi, const uint16_t* __restrict__ Alo, int a_cs, int a_bs, size_t a_z,
    const uint16_t* __restrict__ Bhi, const uint16_t* __restrict__ Blo, int ldb, size_t b_z,
    const float* __restrict__ ADDf,
    const uint16_t* __restrict__ ADDsh, const uint16_t* __restrict__ ADDsl, int add_cs, int add_bs,
    int mask_and, int mask_lim,
    float* __restrict__ O1f, int o1_cs, int o1_bs,
    uint16_t* __restrict__ O1hi, uint16_t* __restrict__ O1lo, int o1s_cs, int o1s_bs, int split_n0, size_t o1_z,
    uint16_t* __restrict__ O2hi, uint16_t* __restrict__ O2lo, int o2_cs, int o2_bs, size_t o2_z) {
  constexpr int FM = BM / 32;
  constexpr int FN = BN / 32;
  __shared__ uint16_t sAh[BM * 32], sAl[BM * 32], sBh[BN * 32], sBl[BN * 32];
  size_t zb = blockIdx.z;
  Ahi += zb * a_z; Alo += zb * a_z;
  Bhi += zb * b_z; Blo += zb * b_z;
  if (O1hi) { O1hi += zb * o1_z; O1lo += zb * o1_z; }
  if (O2hi) { O2hi += zb * o2_z; O2lo += zb * o2_z; }
  int tid = threadIdx.x;
  int lane = tid & 63;
  int wave = tid >> 6;
  int wm = wave >> 1, wn = wave & 1;
  int m0 = blockIdx.y * BM, n0 = blockIdx.x * BN;
  f32x4v acc[FM][FN] = {};
  for (int kt = 0; kt < K; kt += 32) {
    __syncthreads();
#pragma unroll
    for (int qq = 0; qq < BM / 64; ++qq) {
      int off = qq * 4096 + tid * 16;
      int r = off >> 6;
      int cu = (off & 63) >> 1;
      size_t goff = (size_t)(m0 / 4 + (r >> 2)) * a_cs + (size_t)(r & 3) * a_bs + kt + cu;
      __builtin_amdgcn_global_load_lds(
          (const __attribute__((address_space(1))) uint32_t*)(Ahi + goff),
          (__attribute__((address_space(3))) uint32_t*)((char*)sAh + off), 16, 0, 0);
      __builtin_amdgcn_global_load_lds(
          (const __attribute__((address_space(1))) uint32_t*)(Alo + goff),
          (__attribute__((address_space(3))) uint32_t*)((char*)sAl + off), 16, 0, 0);
    }
#pragma unroll
    for (int qq = 0; qq < BN / 64; ++qq) {
      int off = qq * 4096 + tid * 16;
      int r = off >> 6, cu = (off & 63) >> 1;
      size_t goff = (size_t)(n0 + r) * ldb + kt + cu;
      __builtin_amdgcn_global_load_lds(
          (const __attribute__((address_space(1))) uint32_t*)(Bhi + goff),
          (__attribute__((address_space(3))) uint32_t*)((char*)sBh + off), 16, 0, 0);
      __builtin_amdgcn_global_load_lds(
          (const __attribute__((address_space(1))) uint32_t*)(Blo + goff),
          (__attribute__((address_space(3))) uint32_t*)((char*)sBl + off), 16, 0, 0);
    }
    __syncthreads();
    int rsel = lane & 15, ko = (lane >> 4) * 8;
    bf16x8 ah[FM], al[FM], bh[FN], bl[FN];
#pragma unroll
    for (int mf = 0; mf < FM; ++mf) {
      int row = wm * (FM * 16) + mf * 16 + rsel;
      ah[mf] = *reinterpret_cast<const bf16x8*>(sAh + row * 32 + ko);
      al[mf] = *reinterpret_cast<const bf16x8*>(sAl + row * 32 + ko);
    }
#pragma unroll
    for (int nf = 0; nf < FN; ++nf) {
      int row = wn * (FN * 16) + nf * 16 + rsel;
      bh[nf] = *reinterpret_cast<const bf16x8*>(sBh + row * 32 + ko);
      bl[nf] = *reinterpret_cast<const bf16x8*>(sBl + row * 32 + ko);
    }
#pragma unroll
    for (int mf = 0; mf < FM; ++mf)
#pragma unroll
      for (int nf = 0; nf < FN; ++nf) {
        acc[mf][nf] = MFMA(ah[mf], bh[nf], acc[mf][nf], 0, 0, 0);
        acc[mf][nf] = MFMA(ah[mf], bl[nf], acc[mf][nf], 0, 0, 0);
        acc[mf][nf] = MFMA(al[mf], bh[nf], acc[mf][nf], 0, 0, 0);
      }
  }
  int rowg = (lane >> 4) * 4, colg = lane & 15;
#pragma unroll
  for (int mf = 0; mf < FM; ++mf)
#pragma unroll
    for (int nf = 0; nf < FN; ++nf)
#pragma unroll
      for (int r = 0; r < 4; ++r) {
        int m = m0 + wm * (FM * 16) + mf * 16 + rowg + r;
        int n = n0 + wn * (FN * 16) + nf * 16 + colg;
        size_t ro = (size_t)(m >> 2);
        float dot = acc[mf][nf][r];
        float addv = 0.f;
        if (ADDf) addv = ADDf[ro * add_cs + (size_t)(m & 3) * add_bs + n];
        else if (ADDsh) {
          size_t ao = ro * add_cs + (size_t)(m & 3) * add_bs + n;
          addv = b2f(ADDsh[ao]) + b2f(ADDsl[ao]);
        }
        float v;
        if (mask_lim && (((m >> 2) & mask_and) < mask_lim)) v = addv;
        else v = dot + addv;
        if (O1f) O1f[ro * o1_cs + (size_t)(m & 3) * o1_bs + n] = v;
        if (O1hi && n >= split_n0) {
          uint16_t h, l;
          fsplit(v, h, l);
          size_t o = ro * o1s_cs + (size_t)(m & 3) * o1s_bs + (n - split_n0);
          O1hi[o] = h; O1lo[o] = l;
        }
        if (O2hi) {
          uint16_t h, l;
          fsplit(dot, h, l);
          size_t o = (o2_bs == 0) ? ((size_t)n * o2_cs + m)
                                  : (ro * o2_cs + (size_t)(m & 3) * o2_bs + n);
          O2hi[o] = h; O2lo[o] = l;
        }
      }
}

// ---------------- sigma0 -> Z row 0 (4 batch rows, split)
__global__ __launch_bounds__(256) void k_sigma0(const float* __restrict__ starterL,
                                                uint16_t* __restrict__ Z0h, uint16_t* __restrict__ Z0l) {
  int idx = blockIdx.x * 256 + threadIdx.x;   // 4096
  int d = idx & 1023, b = idx >> 10;
  uint16_t h, l;
  fsplit(starterL[d], h, l);
  Z0h[(size_t)b * 1024 + d] = h;
  Z0l[(size_t)b * 1024 + d] = l;
}

// ---------------- X init: row t*4+b: j=t&15; j==0 -> sigma_c (Z row c); else u_{t-1} (PU)
__global__ __launch_bounds__(256) void k_init_x(const uint16_t* __restrict__ Zh, const uint16_t* __restrict__ Zl,
                                                const uint16_t* __restrict__ PUh, const uint16_t* __restrict__ PUl,
                                                uint16_t* __restrict__ Xh, uint16_t* __restrict__ Xl) {
  int idx = blockIdx.x * 256 + threadIdx.x;   // 4096 rows * 256 quads
  int d4 = idx & 255;
  int row = idx >> 8;           // t*4+b
  int b = row & 3, t = row >> 2;
  int j = t & 15, c = t >> 4;
  const uint16_t *sh, *sl;
  size_t so;
  if (j == 0) { sh = Zh; sl = Zl; so = ((size_t)c * 4 + b) * 1024; }
  else { sh = PUh; sl = PUl; so = ((size_t)(t - 1) * 4 + b) * 1024; }
  reinterpret_cast<ushort4*>(Xh + (size_t)row * 1024)[d4] = reinterpret_cast<const ushort4*>(sh + so)[d4];
  reinterpret_cast<ushort4*>(Xl + (size_t)row * 1024)[d4] = reinterpret_cast<const ushort4*>(sl + so)[d4];
}

// ---------------- reorder H_hi [t][b][d] -> Y [b][t][d]
__global__ __launch_bounds__(256) void k_reorder_hi(const uint16_t* __restrict__ Hhi, uint16_t* __restrict__ Y) {
  int idx = blockIdx.x * 256 + threadIdx.x;
  int d4 = idx & (DIMX / 4 - 1);
  int tb = idx >> 8;
  int t = tb >> 2, b = tb & 3;
  ushort4 v = reinterpret_cast<const ushort4*>(Hhi)[idx];
  reinterpret_cast<ushort4*>(Y + (size_t)(b * SEQ + t) * DIMX)[d4] = v;
}

__global__ __launch_bounds__(256) void k_cast_w(const float* __restrict__ src, uint16_t* __restrict__ dst, int n4) {
  int idx = blockIdx.x * 256 + threadIdx.x;
  if (idx >= n4) return;
  float4 v = reinterpret_cast<const float4*>(src)[idx];
  ushort4 o;
  o.x = f2b(v.x); o.y = f2b(v.y); o.z = f2b(v.z); o.w = f2b(v.w);
  reinterpret_cast<ushort4*>(dst)[idx] = o;
}

// ---------------- logits GEMM: bf16 MFMA 128x128
__global__ __launch_bounds__(256) void k_logits(const uint16_t* __restrict__ A,
                                                const uint16_t* __restrict__ Bt,
                                                float* __restrict__ C) {
  __shared__ uint16_t As[128 * 32];
  __shared__ uint16_t Bs[128 * 32];
  int tid = threadIdx.x;
  int bx = blockIdx.x, by = blockIdx.y;
  int lane = tid & 63, wave = tid >> 6;
  int wm = wave >> 1, wn = wave & 1;
  f32x4v acc[4][4] = {};
  const uint16_t* Ag = A + (size_t)by * 128 * 1024;
  const uint16_t* Bg = Bt + (size_t)bx * 128 * 1024;
  for (int kt = 0; kt < 1024; kt += 32) {
    __syncthreads();
#pragma unroll
    for (int qq = 0; qq < 2; ++qq) {
      int off = qq * 4096 + tid * 16;
      int r = off >> 6, cu = (off & 63) >> 1;
      __builtin_amdgcn_global_load_lds(
          (const __attribute__((address_space(1))) uint32_t*)(Ag + (size_t)r * 1024 + kt + cu),
          (__attribute__((address_space(3))) uint32_t*)((char*)As + off), 16, 0, 0);
      __builtin_amdgcn_global_load_lds(
          (const __attribute__((address_space(1))) uint32_t*)(Bg + (size_t)r * 1024 + kt + cu),
          (__attribute__((address_space(3))) uint32_t*)((char*)Bs + off), 16, 0, 0);
    }
    __syncthreads();
    int rsel = lane & 15, ko = (lane >> 4) * 8;
    bf16x8 af[4], bfr[4];
#pragma unroll
    for (int mf = 0; mf < 4; ++mf)
      af[mf] = *reinterpret_cast<const bf16x8*>(As + (wm * 64 + mf * 16 + rsel) * 32 + ko);
#pragma unroll
    for (int nf = 0; nf < 4; ++nf)
      bfr[nf] = *reinterpret_cast<const bf16x8*>(Bs + (wn * 64 + nf * 16 + rsel) * 32 + ko);
#pragma unroll
    for (int mf = 0; mf < 4; ++mf)
#pragma unroll
      for (int nf = 0; nf < 4; ++nf)
        acc[mf][nf] = MFMA(af[mf], bfr[nf], acc[mf][nf], 0, 0, 0);
  }
  int rowg = (lane >> 4) * 4;
  int colg = lane & 15;
#pragma unroll
  for (int mf = 0; mf < 4; ++mf)
#pragma unroll
    for (int nf = 0; nf < 4; ++nf)
#pragma unroll
      for (int r = 0; r < 4; ++r) {
        int m = by * 128 + wm * 64 + mf * 16 + rowg + r;
        int n = bx * 128 + wn * 64 + nf * 16 + colg;
        C[(size_t)m * VOCAB + n] = acc[mf][nf][r];
      }
}

// =========================================================================
extern "C" void kernel_launch(void* const* d_in, const int* in_sizes, int n_in,
                              void* d_out, int out_size, void* d_ws, size_t ws_size,
                              hipStream_t stream) {
  const int* ids = (const int*)d_in[0];
  const float* emb = (const float*)d_in[1];
  const float* W = (const float*)d_in[2];
  const float* outw = (const float*)d_in[3];
  const float* starter = (const float*)d_in[4];
  float* out = (float*)d_out;

  char* wsb = (char*)d_ws;
  size_t off = 0;
  auto alloc = [&](size_t bytes) {
    void* p = wsb + off;
    off = (off + bytes + 255) & ~(size_t)255;
    return p;
  };
  const size_t TB = SEQ * BATCH;
  const size_t MB1 = (size_t)1024 * 1024;
  const size_t kstr = (size_t)NLAYERS * MB1;   // per-power-level stride

  uint16_t* Hh[2] = {(uint16_t*)alloc(TB * DIMX * 2), (uint16_t*)alloc(TB * DIMX * 2)};
  uint16_t* Hl[2] = {(uint16_t*)alloc(TB * DIMX * 2), (uint16_t*)alloc(TB * DIMX * 2)};
  float* P = (float*)alloc(TB * 2 * DIMX * 4);
  uint16_t* PUh = (uint16_t*)alloc(TB * DIMX * 2);
  uint16_t* PUl = (uint16_t*)alloc(TB * DIMX * 2);
  uint16_t* W1h = (uint16_t*)alloc((size_t)NLAYERS * 2048 * 1024 * 2);
  uint16_t* W1l = (uint16_t*)alloc((size_t)NLAYERS * 2048 * 1024 * 2);
  uint16_t* WSh = (uint16_t*)alloc((size_t)NLAYERS * MB1 * 2);
  uint16_t* WSl = (uint16_t*)alloc((size_t)NLAYERS * MB1 * 2);
  uint16_t* T1h = (uint16_t*)alloc((size_t)NLAYERS * MB1 * 2);
  uint16_t* T1l = (uint16_t*)alloc((size_t)NLAYERS * MB1 * 2);
  uint16_t* TPh[2] = {(uint16_t*)alloc((size_t)NLAYERS * MB1 * 2), (uint16_t*)alloc((size_t)NLAYERS * MB1 * 2)};
  uint16_t* TPl[2] = {(uint16_t*)alloc((size_t)NLAYERS * MB1 * 2), (uint16_t*)alloc((size_t)NLAYERS * MB1 * 2)};
  // MP[k][layer], k=0..10 -> A^(2^k)
  uint16_t* MPh = (uint16_t*)alloc((size_t)11 * kstr * 2);
  uint16_t* MPl = (uint16_t*)alloc((size_t)11 * kstr * 2);
  // chunk-sum tree
  uint16_t* R1h = (uint16_t*)alloc((size_t)2048 * 1024 * 2);
  uint16_t* R1l = (uint16_t*)alloc((size_t)2048 * 1024 * 2);
  uint16_t* R2h = (uint16_t*)alloc((size_t)1024 * 1024 * 2);
  uint16_t* R2l = (uint16_t*)alloc((size_t)1024 * 1024 * 2);
  uint16_t* R3h = (uint16_t*)alloc((size_t)512 * 1024 * 2);
  uint16_t* R3l = (uint16_t*)alloc((size_t)512 * 1024 * 2);
  // boundary Z buffers: 256 guard rows + 384 rows
  uint16_t* ZAfull_h = (uint16_t*)alloc((size_t)640 * 1024 * 2);
  uint16_t* ZAfull_l = (uint16_t*)alloc((size_t)640 * 1024 * 2);
  uint16_t* ZBfull_h = (uint16_t*)alloc((size_t)640 * 1024 * 2);
  uint16_t* ZBfull_l = (uint16_t*)alloc((size_t)640 * 1024 * 2);
  uint16_t* Z0h[2] = {ZAfull_h + 256 * 1024, ZBfull_h + 256 * 1024};
  uint16_t* Z0l[2] = {ZAfull_l + 256 * 1024, ZBfull_l + 256 * 1024};
  // X buffers: 32 guard rows + 4096 rows
  uint16_t* XAfull_h = (uint16_t*)alloc((size_t)(32 + 4096) * 1024 * 2);
  uint16_t* XAfull_l = (uint16_t*)alloc((size_t)(32 + 4096) * 1024 * 2);
  uint16_t* XBfull_h = (uint16_t*)alloc((size_t)(32 + 4096) * 1024 * 2);
  uint16_t* XBfull_l = (uint16_t*)alloc((size_t)(32 + 4096) * 1024 * 2);
  uint16_t* X0h[2] = {XAfull_h + 32 * 1024, XBfull_h + 32 * 1024};
  uint16_t* X0l[2] = {XAfull_l + 32 * 1024, XBfull_l + 32 * 1024};
  uint16_t* YSB = (uint16_t*)alloc(TB * DIMX * 2);
  uint16_t* OWB = (uint16_t*)alloc((size_t)VOCAB * DIMX * 2);

  k_split_w<<<NLAYERS * 4096, 256, 0, stream>>>(W, W1h, W1l, WSh, WSl, MPh, MPl);
  k_trans_w<<<dim3(16, 16, NLAYERS), 256, 0, stream>>>(W, T1h, T1l);
  k_cast_w<<<(int)((size_t)VOCAB * DIMX / 4 / 256), 256, 0, stream>>>(outw, OWB, VOCAB * DIMX / 4);
  k_embed_split<<<(int)(TB * DIMX / 4 / 256), 256, 0, stream>>>(ids, emb, Hh[0], Hl[0]);

  // power chain k=1..10: MP[k] = MP[k-1]^2 ; T companion through k=9
  for (int k = 1; k <= 10; ++k) {
    const uint16_t* inMh = MPh + (size_t)(k - 1) * kstr;
    const uint16_t* inMl = MPl + (size_t)(k - 1) * kstr;
    const uint16_t* inTh = (k == 1) ? T1h : TPh[(k - 1) & 1];
    const uint16_t* inTl = (k == 1) ? T1l : TPl[(k - 1) & 1];
    uint16_t* oMh = MPh + (size_t)k * kstr;
    uint16_t* oMl = MPl + (size_t)k * kstr;
    uint16_t* oTh = (k <= 9) ? TPh[k & 1] : nullptr;
    uint16_t* oTl = (k <= 9) ? TPl[k & 1] : nullptr;
    k_mfma<128, 128><<<dim3(8, 8, NLAYERS), 256, 0, stream>>>(
        1024,
        inMh, inMl, 4096, 1024, MB1,
        inTh, inTl, 1024, MB1,
        nullptr, nullptr, nullptr, 0, 0,
        0, 0,
        nullptr, 0, 0,
        oMh, oMl, 4096, 1024, 0, MB1,
        oTh, oTl, 1024, 0, MB1);
  }

  int cur = 0;
  for (int l = 0; l < NLAYERS; ++l) {
    const uint16_t* MPlh = MPh + (size_t)l * MB1;   // + k*kstr per level
    const uint16_t* MPll = MPl + (size_t)l * MB1;

    // [a|u] = H @ W[:,0:1024]^T ; f32 -> P, split(u) -> PU
    k_mfma<128, 128><<<dim3(16, 32, 1), 256, 0, stream>>>(
        1024,
        Hh[cur], Hl[cur], 4096, 1024, 0,
        W1h + (size_t)l * 2048 * 1024, W1l + (size_t)l * 2048 * 1024, 1024, 0,
        nullptr, nullptr, nullptr, 0, 0,
        0, 0,
        P, 8192, 2048,
        PUh, PUl, 4096, 1024, 1024, 0,
        nullptr, nullptr, 0, 1, 0);

    // ---- chunk-sum tree (E_c written straight into Za rows 1..64)
    // level 1: R1[v] = A * u[2v] + u[2v+1]   (M=2048)
    k_mfma<128, 128><<<dim3(8, 16, 1), 256, 0, stream>>>(
        1024,
        PUh, PUl, 8192, 1024, 0,
        MPlh, MPll, 1024, 0,
        nullptr, PUh + 4096, PUl + 4096, 8192, 1024,
        0, 0,
        nullptr, 0, 0,
        R1h, R1l, 4096, 1024, 0, 0,
        nullptr, nullptr, 0, 1, 0);
    // level 2: R2[v] = A^2 * R1[2v] + R1[2v+1]  (M=1024)
    k_mfma<128, 128><<<dim3(8, 8, 1), 256, 0, stream>>>(
        1024,
        R1h, R1l, 8192, 1024, 0,
        MPlh + 1 * kstr, MPll + 1 * kstr, 1024, 0,
        nullptr, R1h + 4096, R1l + 4096, 8192, 1024,
        0, 0,
        nullptr, 0, 0,
        R2h, R2l, 4096, 1024, 0, 0,
        nullptr, nullptr, 0, 1, 0);
    // level 3: R3[v] = A^4 * R2[2v] + R2[2v+1]  (M=512)
    k_mfma<128, 128><<<dim3(8, 4, 1), 256, 0, stream>>>(
        1024,
        R2h, R2l, 8192, 1024, 0,
        MPlh + 2 * kstr, MPll + 2 * kstr, 1024, 0,
        nullptr, R2h + 4096, R2l + 4096, 8192, 1024,
        0, 0,
        nullptr, 0, 0,
        R3h, R3l, 4096, 1024, 0, 0,
        nullptr, nullptr, 0, 1, 0);
    // level 4: E[c] = A^8 * R3[2c] + R3[2c+1] -> Za rows 1..64  (M=256)
    k_mfma<128, 128><<<dim3(8, 2, 1), 256, 0, stream>>>(
        1024,
        R3h, R3l, 8192, 1024, 0,
        MPlh + 3 * kstr, MPll + 3 * kstr, 1024, 0,
        nullptr, R3h + 4096, R3l + 4096, 8192, 1024,
        0, 0,
        nullptr, 0, 0,
        Z0h[0] + 4096, Z0l[0] + 4096, 4096, 1024, 0, 0,
        nullptr, nullptr, 0, 1, 0);
    // sigma0 -> Za row 0
    k_sigma0<<<16, 256, 0, stream>>>(starter + (size_t)l * DIMX, Z0h[0], Z0l[0]);

    // ---- boundary seeded Hillis-Steele over 65 elements (z0=sigma0, z_{c+1}=E_c)
    // step s: z'_i = (i>=p) ? A16^p * z_{i-p} + z_i : z_i ; p = 2^s, s=0..6 ; M=384
    int zc = 0;
    for (int s = 0; s < 7; ++s) {
      int p = 1 << s;
      k_mfma<128, 128><<<dim3(8, 3, 1), 256, 0, stream>>>(
          1024,
          Z0h[zc] - (size_t)p * 4096, Z0l[zc] - (size_t)p * 4096, 4096, 1024, 0,
          MPlh + (size_t)(4 + s) * kstr, MPll + (size_t)(4 + s) * kstr, 1024, 0,
          nullptr, Z0h[zc], Z0l[zc], 4096, 1024,
          1023, p,
          nullptr, 0, 0,
          Z0h[zc ^ 1], Z0l[zc ^ 1], 4096, 1024, 0, 0,
          nullptr, nullptr, 0, 1, 0);
      zc ^= 1;
    }
    // final sigma_c = Z[zc] row c (zc = 1 after 7 steps)

    // ---- X init: X[t] = (t%16==0) ? sigma_{t/16} : u_{t-1}
    k_init_x<<<(int)(TB * 256 / 256), 256, 0, stream>>>(Z0h[zc], Z0l[zc], PUh, PUl, X0h[0], X0l[0]);

    // ---- seeded in-chunk H-S: 4 steps, p=1,2,4,8, B=A^p ; mask (t&15)<p -> passthrough
    int xc = 0;
    for (int s = 0; s < 4; ++s) {
      int p = 1 << s;
      k_mfma<128, 128><<<dim3(8, 32, 1), 256, 0, stream>>>(
          1024,
          X0h[xc] - (size_t)p * 4096, X0l[xc] - (size_t)p * 4096, 4096, 1024, 0,
          MPlh + (size_t)s * kstr, MPll + (size_t)s * kstr, 1024, 0,
          nullptr, X0h[xc], X0l[xc], 4096, 1024,
          15, p,
          nullptr, 0, 0,
          X0h[xc ^ 1], X0l[xc ^ 1], 4096, 1024, 0, 0,
          nullptr, nullptr, 0, 1, 0);
      xc ^= 1;
    }
    // final S in X0[xc] (xc = 0 after 4 steps)

    // H_next = a + S @ W_hs^T (split out)
    k_mfma<128, 128><<<dim3(8, 32, 1), 256, 0, stream>>>(
        1024,
        X0h[xc], X0l[xc], 4096, 1024, 0,
        WSh + (size_t)l * MB1, WSl + (size_t)l * MB1, 1024, 0,
        P, nullptr, nullptr, 8192, 2048,
        0, 0,
        nullptr, 0, 0,
        Hh[cur ^ 1], Hl[cur ^ 1], 4096, 1024, 0, 0,
        nullptr, nullptr, 0, 1, 0);
    cur ^= 1;
  }

  k_reorder_hi<<<(int)(TB * DIMX / 4 / 256), 256, 0, stream>>>(Hh[cur], YSB);
  k_logits<<<dim3(VOCAB / 128, TB / 128), 256, 0, stream>>>(YSB, OWB, out);
}